// Round 6
// baseline (172.550 us; speedup 1.0000x reference)
//
#include <hip/hip_runtime.h>
#include <hip/hip_bf16.h>
#include <stdint.h>

typedef __bf16 bf16_t;
typedef bf16_t bf16x8 __attribute__((ext_vector_type(8)));
typedef float f32x4 __attribute__((ext_vector_type(4)));
typedef float f32x16 __attribute__((ext_vector_type(16)));

#define BM 256
#define BN 256
#define BK 64

// ---------------------------------------------------------------------------
// async global->LDS 16B copy. LDS dest is wave-uniform base; HW adds lane*16.
// ---------------------------------------------------------------------------
__device__ __forceinline__ void gload_lds16(const void* g, void* l) {
  __builtin_amdgcn_global_load_lds(
      (const __attribute__((address_space(1))) uint32_t*)g,
      (__attribute__((address_space(3))) uint32_t*)l, 16, 0, 0);
}

// ---------------------------------------------------------------------------
// fused fp32->bf16 conversion: blocks [0,gx) convert x, [gx,..) convert
// weight (per-out-channel scale folded in). 8 elems/thread, grid-stride.
// ---------------------------------------------------------------------------
__global__ __launch_bounds__(256) void cvt_kernel(
    const float* __restrict__ x, bf16_t* __restrict__ xo, int n8x,
    const float* __restrict__ w, const float* __restrict__ scale,
    bf16_t* __restrict__ wo, int k8, int n8w, int gx) {
  if ((int)blockIdx.x < gx) {
    int stride = gx * blockDim.x;
    for (int i = blockIdx.x * blockDim.x + threadIdx.x; i < n8x; i += stride) {
      const f32x4* p = (const f32x4*)x + 2 * (size_t)i;
      f32x4 a = p[0], b = p[1];
      bf16x8 o;
#pragma unroll
      for (int r = 0; r < 4; ++r) { o[r] = (bf16_t)a[r]; o[r + 4] = (bf16_t)b[r]; }
      *((bf16x8*)xo + i) = o;
    }
  } else {
    int stride = (gridDim.x - gx) * blockDim.x;
    for (int i = (blockIdx.x - gx) * blockDim.x + threadIdx.x; i < n8w;
         i += stride) {
      int row = i / k8;
      float s = scale[row];
      const f32x4* p = (const f32x4*)w + 2 * (size_t)i;
      f32x4 a = p[0], b = p[1];
      bf16x8 o;
#pragma unroll
      for (int r = 0; r < 4; ++r) {
        o[r] = (bf16_t)(a[r] * s);
        o[r + 4] = (bf16_t)(b[r] * s);
      }
      *((bf16x8*)wo + i) = o;
    }
  }
}

// ---------------------------------------------------------------------------
// 256x256 bf16 GEMM, both K-major (B^T), 32x32x16 MFMA.
// 8 waves (2Mx4N), per-wave out 128x64 = 4x2 frags of 32x32 (16 f32 acc each).
// 2 phases per K-tile (one K-half = 2 MFMA K-steps each), single barrier per
// phase. Cross-phase A prefetch (aX/aY alternate); B read in-phase FIRST so
// lgkmcnt(8) drains {B-this + A-this} while the 8 newest (A-next) stay
// outstanding and get serviced under MFMA.
//
// Stage ring (unit-pair K0 = A@+0,B@+32K; K1 = A@+16K,B@+48K; 16KB each):
//   P1(t) stages K1(t+1)->nb ; P2(t) stages K0(t+2)->bb
//   vmcnt(4)@end-P1(t) drains K0(t+1)  [read by P2(t)'s A-prefetch]
//   vmcnt(4)@end-P2(t) drains K1(t+1)  [read by P1(t+1)]
// WAR: every region re-stage is >=1 barrier after its last reader's lgkm wait.
//
// LDS swizzle: chunk-XOR s(row)=(row>>1)&3 at 16B granularity (measured
// 0 bank conflicts). 32x32 read pattern row=lane&31, chunk=(lane>>5)+2*ks
// XOR s(row) covers all 32 banks per 16-lane group (2 lanes/bank = free).
// ---------------------------------------------------------------------------
__global__ __launch_bounds__(512, 2) void gemm256(
    const bf16_t* __restrict__ A, const bf16_t* __restrict__ B,
    const float* __restrict__ bias, float* __restrict__ C,
    int M, int N, int K) {
  __shared__ __attribute__((aligned(16))) char lds[131072];

  const int tid = threadIdx.x;
  const int lane = tid & 63;
  const int wave = tid >> 6;
  const int wm = wave >> 2;   // 0..1  (row half of tile)
  const int wn = wave & 3;    // 0..3  (col quarter of tile)

  // XCD-aware bijective swizzle
  int nwg = gridDim.x;
  int wg = blockIdx.x;
  if ((nwg & 7) == 0) { int cpx = nwg >> 3; wg = (wg & 7) * cpx + (wg >> 3); }
  const int ntn = N / BN;
  const int tm = wg / ntn;
  const int tn = wg % ntn;

  const size_t Kb = (size_t)K * 2;
  const char* gApan = (const char*)A + (size_t)tm * BM * Kb;
  const char* gBpan = (const char*)B + (size_t)tn * BN * Kb;

  // ---- per-lane read geometry (32x32 frags) ----
  const int xs = (lane >> 1) & 3;          // swizzle term s(row), row = lane&31
  const int hi = lane >> 5;                // k-group within a K-step
  const int cs0 = ((hi ^ xs) << 4);        // chunk bytes, K-step 0 of unit
  const int cs1 = (((hi + 2) ^ xs) << 4);  // chunk bytes, K-step 1 of unit
  const int aAddr = wm * 8192 + (lane & 31) * 64;  // + fr*2048 + cs{0,1}
  const int bAddr = wn * 4096 + (lane & 31) * 64;  // + fc*2048 + cs{0,1}

  // ---- staging offsets (unchanged, verified conflict-free) ----
  size_t srcoff[2];
  int ldst[2];
#pragma unroll
  for (int s = 0; s < 2; ++s) {
    int r = (wave * 2 + s) * 16 + (lane >> 2);
    int c = (lane & 3) ^ ((lane >> 3) & 3);
    srcoff[s] = (size_t)r * Kb + (size_t)(c << 4);
    ldst[s] = (wave * 2 + s) * 1024;
  }

#define STAGE_U(dstbase, pan, kbyte)                                          \
  {                                                                           \
    gload_lds16((pan) + srcoff[0] + (size_t)(kbyte), lds + (dstbase) + ldst[0]); \
    gload_lds16((pan) + srcoff[1] + (size_t)(kbyte), lds + (dstbase) + ldst[1]); \
  }
#define STAGE_K0(buf, tt)                                                     \
  { STAGE_U((buf) + 0,     gApan, (size_t)(tt)*128);                          \
    STAGE_U((buf) + 32768, gBpan, (size_t)(tt)*128); }
#define STAGE_K1(buf, tt)                                                     \
  { STAGE_U((buf) + 16384, gApan, (size_t)(tt)*128 + 64);                     \
    STAGE_U((buf) + 49152, gBpan, (size_t)(tt)*128 + 64); }
#define RD_B4(ub)                                                             \
  _Pragma("unroll") for (int fc_ = 0; fc_ < 2; ++fc_) {                       \
    bfr[fc_][0] = *(const bf16x8*)(lds + (ub) + bAddr + fc_ * 2048 + cs0);    \
    bfr[fc_][1] = *(const bf16x8*)(lds + (ub) + bAddr + fc_ * 2048 + cs1);    \
  }
#define RD_A8(dst, ub)                                                        \
  _Pragma("unroll") for (int fr_ = 0; fr_ < 4; ++fr_) {                       \
    dst[fr_][0] = *(const bf16x8*)(lds + (ub) + aAddr + fr_ * 2048 + cs0);    \
    dst[fr_][1] = *(const bf16x8*)(lds + (ub) + aAddr + fr_ * 2048 + cs1);    \
  }
#define MFMA16(aU)                                                            \
  __builtin_amdgcn_s_setprio(1);                                              \
  _Pragma("unroll") for (int fr_ = 0; fr_ < 4; ++fr_)                         \
      _Pragma("unroll") for (int fc_ = 0; fc_ < 2; ++fc_) {                   \
        acc[fr_][fc_] = __builtin_amdgcn_mfma_f32_32x32x16_bf16(              \
            aU[fr_][0], bfr[fc_][0], acc[fr_][fc_], 0, 0, 0);                 \
        acc[fr_][fc_] = __builtin_amdgcn_mfma_f32_32x32x16_bf16(              \
            aU[fr_][1], bfr[fc_][1], acc[fr_][fc_], 0, 0, 0);                 \
      }                                                                       \
  __builtin_amdgcn_s_setprio(0);
#define WAIT_LGKM(n) asm volatile("s_waitcnt lgkmcnt(" #n ")" ::: "memory")
#define WAIT_VM(n)   asm volatile("s_waitcnt vmcnt(" #n ")" ::: "memory")
#define SCHED0()     __builtin_amdgcn_sched_barrier(0)
#define BAR()        __builtin_amdgcn_s_barrier()

  f32x16 acc[4][2];
#pragma unroll
  for (int fr = 0; fr < 4; ++fr)
#pragma unroll
    for (int fc = 0; fc < 2; ++fc) acc[fr][fc] = (f32x16)0.0f;

  const int NT = K / BK;

  // ---- prologue: K0(0), K1(0), K0(1); drain K0(0)+K1(0), K0(1) in flight ----
  STAGE_K0(0, 0);
  STAGE_K1(0, 0);
  if (NT > 1) {
    STAGE_K0(65536, 1);
    WAIT_VM(4);
  } else {
    WAIT_VM(0);
  }
  SCHED0();
  BAR();

  bf16x8 aX[4][2], aY[4][2], bfr[2][2];
  RD_A8(aX, 0);   // A-K0(0); completion enforced by P1(0)'s lgkm(8)

  for (int t = 0; t < NT; ++t) {
    const int bb = (t & 1) << 16;
    const int nb = bb ^ 65536;
    const bool st1 = (t + 1) < NT;
    const bool st2 = (t + 2) < NT;

    // ---- P1: MFMA(aX, B-K0) ; read B-K0 + prefetch aY=A-K1(t) ----
    RD_B4(bb + 32768);
    RD_A8(aY, bb + 16384);
    if (st1) STAGE_K1(nb, t + 1);
    WAIT_LGKM(8);
    SCHED0();
    MFMA16(aX);
    if (st1) { WAIT_VM(4); } else { WAIT_VM(0); }
    SCHED0();
    BAR();

    // ---- P2: MFMA(aY, B-K1) ; read B-K1 + prefetch aX=A-K0(t+1) ----
    RD_B4(bb + 49152);
    if (st1) RD_A8(aX, nb);
    if (st2) STAGE_K0(bb, t + 2);
    if (st1) { WAIT_LGKM(8); } else { WAIT_LGKM(0); }
    SCHED0();
    MFMA16(aY);
    if (st2) { WAIT_VM(4); } else { WAIT_VM(0); }
    SCHED0();
    BAR();
  }
#undef STAGE_U
#undef STAGE_K0
#undef STAGE_K1
#undef RD_B4
#undef RD_A8
#undef MFMA16
#undef WAIT_LGKM
#undef WAIT_VM
#undef SCHED0
#undef BAR

  // ---- epilogue. 32x32 C/D: col=lane&31, row=(reg&3)+8*(reg>>2)+4*(lane>>5)
  const int row0 = tm * BM + wm * 128;
  const int col0 = tn * BN + wn * 64;
  const int lrow = (lane >> 5) << 2;
  const int lcol = lane & 31;
#pragma unroll
  for (int fc = 0; fc < 2; ++fc) {
    int c = col0 + fc * 32 + lcol;
    float bv = bias[c];
#pragma unroll
    for (int fr = 0; fr < 4; ++fr) {
#pragma unroll
      for (int reg = 0; reg < 16; ++reg) {
        int r = row0 + fr * 32 + (reg & 3) + ((reg >> 2) << 3) + lrow;
        C[(size_t)r * N + c] = acc[fr][fc][reg] + bv;
      }
    }
  }
}

// ---------------------------------------------------------------------------
// fallback: naive fp32 (only if workspace/shape unsuitable — correctness net)
// ---------------------------------------------------------------------------
__global__ void fallback_gemm(const float* __restrict__ x,
                              const float* __restrict__ w,
                              const float* __restrict__ s,
                              const float* __restrict__ b,
                              float* __restrict__ out, int M, int N, int K) {
  int o = blockIdx.x * blockDim.x + threadIdx.x;
  if (o >= M * N) return;
  int m = o / N, n = o % N;
  const float* xr = x + (size_t)m * K;
  const float* wr = w + (size_t)n * K;
  float acc = 0.f;
  for (int k = 0; k < K; ++k) acc += xr[k] * wr[k];
  out[o] = acc * s[n] + b[n];
}

extern "C" void kernel_launch(void* const* d_in, const int* in_sizes, int n_in,
                              void* d_out, int out_size, void* d_ws,
                              size_t ws_size, hipStream_t stream) {
  const float* x = (const float*)d_in[0];
  const float* w = (const float*)d_in[1];
  const float* sc = (const float*)d_in[2];
  const float* bias = (const float*)d_in[3];
  float* out = (float*)d_out;

  const int N = in_sizes[2];        // out_features (weight_scale length)
  const int K = in_sizes[1] / N;    // in_features
  const int M = in_sizes[0] / K;    // tokens

  const size_t need = ((size_t)M * K + (size_t)N * K) * sizeof(bf16_t);
  const bool fast = (ws_size >= need) && (M % BM == 0) && (N % BN == 0) &&
                    (K % BK == 0) && (K / BK >= 1);

  if (fast) {
    bf16_t* xb = (bf16_t*)d_ws;
    bf16_t* wb = xb + (size_t)M * K;

    int n8x = (M * K) / 8;
    int n8w = (N * K) / 8;
    const int gx = 2048;
    cvt_kernel<<<gx + 2048, 256, 0, stream>>>(x, xb, n8x, w, sc, wb, K / 8,
                                              n8w, gx);

    dim3 grid((M / BM) * (N / BN));
    gemm256<<<grid, 512, 0, stream>>>(xb, wb, bias, out, M, N, K);
  } else {
    int total = M * N;
    fallback_gemm<<<(total + 255) / 256, 256, 0, stream>>>(x, w, sc, bias, out,
                                                           M, N, K);
  }
}